// Round 1
// baseline (702.381 us; speedup 1.0000x reference)
//
#include <hip/hip_runtime.h>

// ---- problem constants (from setup_inputs) ----
#define BQ    128   // batch
#define DQ    768   // query/key dim
#define POOL  100   // e-prompt pool size
#define TOPK  5
#define LG    6     // g layers
#define LE    6     // e layers
#define GLEN  5
#define ELEN  20
#define NH    12
#define HD    64

// g_out: [LG,2,B,NH,GLEN,HD]  = 6*2*128*12*5*64   = 5,898,240 floats = 1,474,560 f4
// e_out: [LE,2,B,NH,TOPK*ELEN,HD] = 6*2*128*12*100*64 = 117,964,800 floats = 29,491,200 f4
#define G_OUT_F4 1474560
#define E_OUT_F4 29491200

// ---------------------------------------------------------------------------
// Kernel 1: cosine-sim top-5 per query row.
// One block (256 thr = 4 waves) per query. q-norm is constant per row so it
// cannot change the ordering -> skip it. Key norm matters; eps guard kept.
// Tie-break: strict '>' scan keeps the lowest index first, matching
// jax.lax.top_k semantics.
// ---------------------------------------------------------------------------
__global__ void __launch_bounds__(256)
topk_kernel(const float* __restrict__ q,
            const float* __restrict__ keys,
            int* __restrict__ idx_out) {
    const int b = blockIdx.x;
    __shared__ float qs[DQ];
    __shared__ float sims[POOL];

    const int t    = threadIdx.x;
    const int wave = t >> 6;
    const int lane = t & 63;

    for (int i = t; i < DQ; i += 256) qs[i] = q[b * DQ + i];
    __syncthreads();

    for (int p = wave; p < POOL; p += 4) {
        const float* kp = keys + p * DQ;
        float dot = 0.f, ksq = 0.f;
        for (int i = lane; i < DQ; i += 64) {
            float kv = kp[i];
            dot += qs[i] * kv;
            ksq += kv * kv;
        }
        #pragma unroll
        for (int off = 32; off > 0; off >>= 1) {
            dot += __shfl_down(dot, off);
            ksq += __shfl_down(ksq, off);
        }
        if (lane == 0) {
            float n = sqrtf(ksq);
            sims[p] = dot / fmaxf(n, 1e-12f);
        }
    }
    __syncthreads();

    if (t == 0) {
        #pragma unroll
        for (int k = 0; k < TOPK; k++) {
            float best = -3.0e38f;
            int   bi   = 0;
            for (int p = 0; p < POOL; p++) {
                float v = sims[p];
                if (v > best) { best = v; bi = p; }
            }
            idx_out[b * TOPK + k] = bi;
            sims[bi] = -3.0e38f;
        }
    }
}

// ---------------------------------------------------------------------------
// Kernel 2: g_out broadcast+transpose. One thread per output float4, linear
// output order (streaming coalesced writes). Source (184 KB) is cache-hot.
// out[l,s,b,h,gl,d] = g_prompt[l,s,gl,h,d]
// ---------------------------------------------------------------------------
__global__ void __launch_bounds__(256)
g_kernel(const float4* __restrict__ g, float4* __restrict__ out) {
    int o = blockIdx.x * 256 + threadIdx.x;
    if (o >= G_OUT_F4) return;
    int d4 = o & 15;
    int r  = o >> 4;          // (ls, b, h, gl)
    int gl = r % GLEN;  r /= GLEN;
    int h  = r % NH;    r /= NH;
    /* b */             r >>= 7;   // drop b (broadcast dim)
    // r == l*2+s
    int src = ((r * GLEN + gl) * NH + h) * (HD / 4) + d4;
    out[o] = g[src];
}

// ---------------------------------------------------------------------------
// Kernel 3: e_out gather. One thread per output float4 in linear output
// order. 16 consecutive lanes = one contiguous 256B run on both sides.
// out[l,s,b,h,k*ELEN+e,d] = pool[idx[b,k], l, s, e, h, d]
// pool f4 index = ((p*12 + ls)*ELEN + e)*NH*16 stuff -> see below
// ---------------------------------------------------------------------------
__global__ void __launch_bounds__(256)
e_kernel(const float4* __restrict__ pool,
         const int* __restrict__ idx,
         float4* __restrict__ out) {
    int o = blockIdx.x * 256 + threadIdx.x;
    if (o >= E_OUT_F4) return;
    int d4 = o & 15;
    int r  = o >> 4;                    // (ls, b, h, ke)
    int ke = r % (TOPK * ELEN); r /= (TOPK * ELEN);
    int h  = r % NH;            r /= NH;
    int b  = r & 127;           r >>= 7;
    int ls = r;                         // l*2+s in [0,12)
    int k  = ke / ELEN;
    int e  = ke - k * ELEN;
    int p  = idx[b * TOPK + k];
    // pool linear f4: ((((p*LE+l)*2+s)*ELEN+e)*NH+h)*(HD/4)+d4
    //              = (((p*12 + ls)*ELEN + e)*NH + h)*16 + d4
    int src = (((p * 12 + ls) * ELEN + e) * NH + h) * (HD / 4) + d4;
    out[G_OUT_F4 + o] = pool[src];
}

extern "C" void kernel_launch(void* const* d_in, const int* in_sizes, int n_in,
                              void* d_out, int out_size, void* d_ws, size_t ws_size,
                              hipStream_t stream) {
    const float*  query = (const float*)d_in[0];
    const float4* gprm  = (const float4*)d_in[1];
    const float4* pool  = (const float4*)d_in[2];
    const float*  keys  = (const float*)d_in[3];
    float4*       out   = (float4*)d_out;
    int*          idx   = (int*)d_ws;   // BQ*TOPK ints = 2560 B

    topk_kernel<<<BQ, 256, 0, stream>>>(query, keys, idx);
    g_kernel<<<G_OUT_F4 / 256, 256, 0, stream>>>(gprm, out);
    e_kernel<<<E_OUT_F4 / 256, 256, 0, stream>>>(pool, idx, out);
}